// Round 1
// baseline (620.812 us; speedup 1.0000x reference)
//
#include <hip/hip_runtime.h>

typedef __bf16 bf16x8 __attribute__((ext_vector_type(8)));
typedef float f32x4 __attribute__((ext_vector_type(4)));

#define MFMA16(a, b, c) __builtin_amdgcn_mfma_f32_16x16x32_bf16(a, b, c, 0, 0, 0)

__device__ inline bf16x8 ldcvt8(const float* p) {
  const float4* q = (const float4*)p;
  float4 a = q[0], b = q[1];
  bf16x8 r;
  r[0] = (__bf16)a.x; r[1] = (__bf16)a.y; r[2] = (__bf16)a.z; r[3] = (__bf16)a.w;
  r[4] = (__bf16)b.x; r[5] = (__bf16)b.y; r[6] = (__bf16)b.z; r[7] = (__bf16)b.w;
  return r;
}
__device__ inline bf16x8 ldcvt8(const __bf16* p) { return *(const bf16x8*)p; }

__device__ inline float qmax4(float v) {
  v = fmaxf(v, __shfl_xor(v, 1));
  v = fmaxf(v, __shfl_xor(v, 2));
  v = fmaxf(v, __shfl_xor(v, 4));
  v = fmaxf(v, __shfl_xor(v, 8));
  return v;
}
__device__ inline float qsum4(float v) {
  v += __shfl_xor(v, 1);
  v += __shfl_xor(v, 2);
  v += __shfl_xor(v, 4);
  v += __shfl_xor(v, 8);
  return v;
}

// Convert f32 -> bf16 with scale, 8 elements per thread.
__global__ void cvt_scale(const float* __restrict__ src, __bf16* __restrict__ dst,
                          int n8, float scale) {
  int i = blockIdx.x * blockDim.x + threadIdx.x;
  if (i >= n8) return;
  const float4* p = (const float4*)(src + i * 8);
  float4 a = p[0], b = p[1];
  bf16x8 r;
  r[0] = (__bf16)(a.x * scale); r[1] = (__bf16)(a.y * scale);
  r[2] = (__bf16)(a.z * scale); r[3] = (__bf16)(a.w * scale);
  r[4] = (__bf16)(b.x * scale); r[5] = (__bf16)(b.y * scale);
  r[6] = (__bf16)(b.z * scale); r[7] = (__bf16)(b.w * scale);
  *(bf16x8*)(dst + i * 8) = r;
}

// Materialize relative-position bias: bias[h][q][k], h-major for coalesced reads.
__global__ void bias_build(const float* __restrict__ rpb, float* __restrict__ bias) {
  int i = blockIdx.x * blockDim.x + threadIdx.x;
  if (i >= 343 * 343) return;
  int q = i / 343, k = i % 343;
  int q0 = q / 49, q1 = (q / 7) % 7, q2 = q % 7;
  int k0 = k / 49, k1 = (k / 7) % 7, k2 = k % 7;
  int idx = ((q0 - k0 + 6) * 13 + (q1 - k1 + 6)) * 13 + (q2 - k2 + 6);
  const float* row = rpb + idx * 16;
#pragma unroll
  for (int h = 0; h < 16; h++) bias[h * 117649 + i] = row[h];
}

// C = A(MxK) @ B(NxK)^T, bf16 MFMA, 128x128 tile, BK=32, 256 thr = 4 waves (2x2).
// MODE 0: scatter epilogue -> K,V bf16 [b][h][n][hd].  MODE 1: +bias, f32 out.
template <typename TA, typename TB, int MODE>
__global__ void __launch_bounds__(256, 2)
gemm_bt(const TA* __restrict__ A, const TB* __restrict__ B, const int K,
        void* __restrict__ out0, void* __restrict__ out1,
        const float* __restrict__ pbias) {
  __shared__ __bf16 As[128 * 32];
  __shared__ __bf16 Bs[128 * 32];
  const int tid = threadIdx.x;
  const int lane = tid & 63, wave = tid >> 6;
  const int quad = lane >> 4, l15 = lane & 15;
  const int wm = wave >> 1, wn = wave & 1;
  const int m0 = blockIdx.y * 128, n0 = blockIdx.x * 128;
  const int sr = tid >> 2, sc = (tid & 3) * 8;
  f32x4 acc[4][4] = {};
  for (int k0 = 0; k0 < K; k0 += 32) {
    bf16x8 a0 = ldcvt8(A + (m0 + sr) * K + k0 + sc);
    bf16x8 a1 = ldcvt8(A + (m0 + sr + 64) * K + k0 + sc);
    bf16x8 b0 = ldcvt8(B + (n0 + sr) * K + k0 + sc);
    bf16x8 b1 = ldcvt8(B + (n0 + sr + 64) * K + k0 + sc);
    __syncthreads();
    *(bf16x8*)(As + sr * 32 + sc) = a0;
    *(bf16x8*)(As + (sr + 64) * 32 + sc) = a1;
    *(bf16x8*)(Bs + sr * 32 + sc) = b0;
    *(bf16x8*)(Bs + (sr + 64) * 32 + sc) = b1;
    __syncthreads();
    bf16x8 af[4], bfr[4];
#pragma unroll
    for (int i = 0; i < 4; i++) {
      af[i] = *(const bf16x8*)(As + (wm * 64 + i * 16 + l15) * 32 + quad * 8);
      bfr[i] = *(const bf16x8*)(Bs + (wn * 64 + i * 16 + l15) * 32 + quad * 8);
    }
#pragma unroll
    for (int i = 0; i < 4; i++)
#pragma unroll
      for (int j = 0; j < 4; j++)
        acc[i][j] = MFMA16(af[i], bfr[j], acc[i][j]);
  }
#pragma unroll
  for (int i = 0; i < 4; i++) {
    const int rowb = m0 + wm * 64 + i * 16 + quad * 4;
#pragma unroll
    for (int r = 0; r < 4; r++) {
      const int row = rowb + r;
      if constexpr (MODE == 0) {
        const int bb = row / 343, pos = row % 343;
#pragma unroll
        for (int j = 0; j < 4; j++) {
          const int col = n0 + wn * 64 + j * 16 + l15;
          const int two = col >> 9, hh = (col >> 5) & 15, d = col & 31;
          __bf16* dst = two ? (__bf16*)out1 : (__bf16*)out0;
          dst[((bb * 16 + hh) * 343 + pos) * 32 + d] = (__bf16)acc[i][j][r];
        }
      } else {
        float* o = (float*)out0;
#pragma unroll
        for (int j = 0; j < 4; j++) {
          const int col = n0 + wn * 64 + j * 16 + l15;
          o[row * 512 + col] = acc[i][j][r] + pbias[col];
        }
      }
    }
  }
}

// One workgroup per (b, h): full K/V^T in LDS, per-wave 16-row Q tiles.
__global__ void __launch_bounds__(512, 2)
attn_win(const __bf16* __restrict__ qs, const __bf16* __restrict__ kk,
         const __bf16* __restrict__ vv, const float* __restrict__ bias,
         const float* __restrict__ mask, __bf16* __restrict__ ao) {
  __shared__ __bf16 Ks[352 * 40];   // keys padded to 352, row stride 40 (b128-clean)
  __shared__ __bf16 Vt[32 * 360];   // V transposed [hd][key], stride 360
  __shared__ __bf16 Pb[8 * 16 * 40];  // per-wave P staging (C-layout -> A-layout)
  const int bh = blockIdx.x;
  const int b = bh >> 4, h = bh & 15;
  const int tid = threadIdx.x;
  const int lane = tid & 63, wave = tid >> 6;
  const int quad = lane >> 4, l15 = lane & 15;
  const __bf16* ksrc = kk + (b * 16 + h) * 10976;
  const __bf16* vsrc = vv + (b * 16 + h) * 10976;
  for (int i = tid; i < 352 * 4; i += 512) {
    const int row = i >> 2, seg = (i & 3) * 8;
    bf16x8 val;
    if (row < 343) {
      val = *(const bf16x8*)(ksrc + row * 32 + seg);
    } else {
#pragma unroll
      for (int e = 0; e < 8; e++) val[e] = (__bf16)0.f;
    }
    *(bf16x8*)(Ks + row * 40 + seg) = val;
  }
  for (int i = tid; i < 32 * 17; i += 512)
    Vt[(i / 17) * 360 + 343 + (i % 17)] = (__bf16)0.f;  // zero key pad (poison -> NaN guard)
  for (int i = tid; i < 10976; i += 512)
    Vt[(i & 31) * 360 + (i >> 5)] = vsrc[i];
  __syncthreads();

  const int b2 = b >> 6, w = b & 63;
  const float* maskp = mask + w * 117649;
  const float* biasp = bias + h * 117649;
  const __bf16* qbase = qs + (b2 * 16 + h) * 10976;

  for (int qt = wave; qt < 22; qt += 8) {
    const int rbase = qt * 16 + quad * 4;
    const int arow = qt * 16 + l15;
    const int arowc = arow < 343 ? arow : 342;  // clamp; padded rows discarded at store
    bf16x8 aq = *(const bf16x8*)(qbase + arowc * 32 + quad * 8);
    f32x4 s[22];
#pragma unroll
    for (int t = 0; t < 22; t++) {
      bf16x8 bk = *(const bf16x8*)(Ks + (t * 16 + l15) * 40 + quad * 8);
      f32x4 z = {0.f, 0.f, 0.f, 0.f};
      s[t] = MFMA16(aq, bk, z);
    }
    float mrow[4] = {-1e30f, -1e30f, -1e30f, -1e30f};
#pragma unroll
    for (int t = 0; t < 22; t++) {
      const int col = t * 16 + l15;
      const bool cv = col < 343;
      const int ccol = cv ? col : 0;
#pragma unroll
      for (int r = 0; r < 4; r++) {
        const int rr = rbase + r;
        const int rowc = rr < 343 ? rr : 342;
        const int off = rowc * 343 + ccol;
        float sv = s[t][r] + biasp[off] + maskp[off];
        sv = cv ? sv : -1e30f;
        s[t][r] = sv;
        mrow[r] = fmaxf(mrow[r], sv);
      }
    }
#pragma unroll
    for (int r = 0; r < 4; r++) mrow[r] = qmax4(mrow[r]);
    float lsum[4] = {0.f, 0.f, 0.f, 0.f};
#pragma unroll
    for (int t = 0; t < 22; t++)
#pragma unroll
      for (int r = 0; r < 4; r++) {
        const float p = __builtin_amdgcn_exp2f(1.4426950408889634f * (s[t][r] - mrow[r]));
        s[t][r] = p;
        lsum[r] += p;
      }
#pragma unroll
    for (int r = 0; r < 4; r++) lsum[r] = qsum4(lsum[r]);
    f32x4 o0 = {0.f, 0.f, 0.f, 0.f}, o1 = {0.f, 0.f, 0.f, 0.f};
    __bf16* pb = Pb + wave * 640;
#pragma unroll
    for (int c = 0; c < 11; c++) {
#pragma unroll
      for (int t2 = 0; t2 < 2; t2++)
#pragma unroll
        for (int r = 0; r < 4; r++)
          pb[(quad * 4 + r) * 40 + t2 * 16 + l15] = (__bf16)s[2 * c + t2][r];
      __threadfence_block();  // wave-private buffer: compiler barrier + lgkm drain
      bf16x8 ap = *(const bf16x8*)(pb + l15 * 40 + quad * 8);
      bf16x8 bv0 = *(const bf16x8*)(Vt + l15 * 360 + c * 32 + quad * 8);
      bf16x8 bv1 = *(const bf16x8*)(Vt + (16 + l15) * 360 + c * 32 + quad * 8);
      o0 = MFMA16(ap, bv0, o0);
      o1 = MFMA16(ap, bv1, o1);
    }
#pragma unroll
    for (int r = 0; r < 4; r++) {
      const int row = rbase + r;
      if (row < 343) {
        const float inv = 1.f / lsum[r];
        __bf16* op = ao + (b * 343 + row) * 512 + h * 32;
        op[l15] = (__bf16)(o0[r] * inv);
        op[16 + l15] = (__bf16)(o1[r] * inv);
      }
    }
  }
}

extern "C" void kernel_launch(void* const* d_in, const int* in_sizes, int n_in,
                              void* d_out, int out_size, void* d_ws, size_t ws_size,
                              hipStream_t stream) {
  (void)in_sizes; (void)n_in; (void)out_size; (void)ws_size;
  const float* x      = (const float*)d_in[0];
  const float* mask   = (const float*)d_in[4];
  const float* qg     = (const float*)d_in[5];
  const float* kv_w   = (const float*)d_in[6];
  const float* proj_w = (const float*)d_in[7];
  const float* proj_b = (const float*)d_in[8];
  const float* rpb    = (const float*)d_in[9];

  // Workspace layout (all 16B aligned), total 143,807,552 bytes:
  char* ws = (char*)d_ws;
  __bf16* q_bf = (__bf16*)(ws);               //  1,404,928 B  q*SCALE bf16 [2][16][343][32]
  float* bias  = (float*)(ws + 1404928);      //  7,529,536 B  [16][343][343]
  __bf16* kb   = (__bf16*)(ws + 8934464);     // 44,957,696 B  K bf16 [128][16][343][32]
  __bf16* vb   = (__bf16*)(ws + 53892160);    // 44,957,696 B  V bf16 [128][16][343][32]
  __bf16* aob  = (__bf16*)(ws + 98849856);    // 44,957,696 B  attn out bf16 [128][343][512]

  const float SCALE = 0.17677669529663687f;  // 32^-0.5

  cvt_scale<<<172, 256, 0, stream>>>(qg, q_bf, 43904, SCALE);
  bias_build<<<460, 256, 0, stream>>>(rpb, bias);
  gemm_bt<float, float, 0><<<dim3(8, 343), 256, 0, stream>>>(x, kv_w, 512, kb, vb, nullptr);
  attn_win<<<2048, 512, 0, stream>>>(q_bf, kb, vb, bias, mask, aob);
  gemm_bt<__bf16, float, 1><<<dim3(4, 343), 256, 0, stream>>>(aob, proj_w, 512, d_out, nullptr, proj_b);
}

// Round 4
// 445.657 us; speedup vs baseline: 1.3930x; 1.3930x over previous
//
#include <hip/hip_runtime.h>

typedef __bf16 bf16x8 __attribute__((ext_vector_type(8)));
typedef float f32x4 __attribute__((ext_vector_type(4)));

#define MFMA16(a, b, c) __builtin_amdgcn_mfma_f32_16x16x32_bf16(a, b, c, 0, 0, 0)
#define LOG2E 1.4426950408889634f

typedef __attribute__((address_space(3))) void lds_void;
typedef __attribute__((address_space(1))) const void gbl_void;
__device__ inline void glds16(const __bf16* g, __bf16* l) {
  __builtin_amdgcn_global_load_lds((gbl_void*)g, (lds_void*)l, 16, 0, 0);
}

__device__ inline float qsum4(float v) {
  v += __shfl_xor(v, 1);
  v += __shfl_xor(v, 2);
  v += __shfl_xor(v, 4);
  v += __shfl_xor(v, 8);
  return v;
}

// Convert f32 -> bf16 with scale, 8 elements per thread.
__global__ void cvt_scale(const float* __restrict__ src, __bf16* __restrict__ dst,
                          int n8, float scale) {
  int i = blockIdx.x * blockDim.x + threadIdx.x;
  if (i >= n8) return;
  const float4* p = (const float4*)(src + i * 8);
  float4 a = p[0], b = p[1];
  bf16x8 r;
  r[0] = (__bf16)(a.x * scale); r[1] = (__bf16)(a.y * scale);
  r[2] = (__bf16)(a.z * scale); r[3] = (__bf16)(a.w * scale);
  r[4] = (__bf16)(b.x * scale); r[5] = (__bf16)(b.y * scale);
  r[6] = (__bf16)(b.z * scale); r[7] = (__bf16)(b.w * scale);
  *(bf16x8*)(dst + i * 8) = r;
}

// Pack rel-pos bias into MFMA C-fragment order: [h][qt][tp][lane][t2*4+r], bf16,
// pre-scaled by log2(e), pad (row/col>=343) baked as -1e30.
__global__ void pack_bias(const float* __restrict__ rpb, __bf16* __restrict__ dst) {
  int i = blockIdx.x * blockDim.x + threadIdx.x;
  if (i >= 16 * 15488) return;
  int h = i / 15488, rem = i % 15488;   // 15488 = 22*11*64
  int qt = rem / 704, rem2 = rem % 704; // 704 = 11*64
  int tp = rem2 >> 6, lane = rem2 & 63;
  int quad = lane >> 4, l15 = lane & 15;
  bf16x8 v;
#pragma unroll
  for (int t2 = 0; t2 < 2; t2++)
#pragma unroll
    for (int r = 0; r < 4; r++) {
      int row = qt * 16 + quad * 4 + r;
      int col = (tp * 2 + t2) * 16 + l15;
      float val = -1e30f;
      if (row < 343 && col < 343) {
        int q0 = row / 49, q1 = (row / 7) % 7, q2 = row % 7;
        int k0 = col / 49, k1 = (col / 7) % 7, k2 = col % 7;
        int idx = ((q0 - k0 + 6) * 13 + (q1 - k1 + 6)) * 13 + (q2 - k2 + 6);
        val = rpb[idx * 16 + h] * LOG2E;
      }
      v[t2 * 4 + r] = (__bf16)val;
    }
  *(bf16x8*)(dst + i * 8) = v;
}

// Same packing for the window mask: [w][qt][tp][lane][8].
__global__ void pack_mask(const float* __restrict__ mask, __bf16* __restrict__ dst) {
  int i = blockIdx.x * blockDim.x + threadIdx.x;
  if (i >= 64 * 15488) return;
  int w = i / 15488, rem = i % 15488;
  int qt = rem / 704, rem2 = rem % 704;
  int tp = rem2 >> 6, lane = rem2 & 63;
  int quad = lane >> 4, l15 = lane & 15;
  const float* s = mask + w * 117649;
  bf16x8 v;
#pragma unroll
  for (int t2 = 0; t2 < 2; t2++)
#pragma unroll
    for (int r = 0; r < 4; r++) {
      int row = qt * 16 + quad * 4 + r;
      int col = (tp * 2 + t2) * 16 + l15;
      float val = (row < 343 && col < 343) ? s[row * 343 + col] * LOG2E : -1e30f;
      v[t2 * 4 + r] = (__bf16)val;
    }
  *(bf16x8*)(dst + i * 8) = v;
}

// C = A(MxK) @ B(NxK)^T, bf16 in, 128x128 tile, BK=32, global_load_lds staging.
// MODE 0: scatter epilogue -> K,V bf16 [b][h][n][hd].  MODE 1: +bias, f32 out.
template <int MODE>
__global__ void __launch_bounds__(256, 2)
gemm_async(const __bf16* __restrict__ A, const __bf16* __restrict__ B, const int K,
           void* __restrict__ out0, void* __restrict__ out1,
           const float* __restrict__ pbias) {
  __shared__ __bf16 As[128 * 32];
  __shared__ __bf16 Bs[128 * 32];
  const int tid = threadIdx.x;
  const int lane = tid & 63, wave = tid >> 6;
  const int quad = lane >> 4, l15 = lane & 15;
  const int wm = wave >> 1, wn = wave & 1;
  const int m0 = blockIdx.y * 128, n0 = blockIdx.x * 128;
  const int sr = lane >> 2, sc = (lane & 3) * 8;
  const __bf16* Ab = A + (m0 + wave * 16 + sr) * K + sc;
  const __bf16* Bb = B + (n0 + wave * 16 + sr) * K + sc;
  __bf16* Asl = As + wave * 512;  // wave-uniform LDS base; HW adds lane*16B
  __bf16* Bsl = Bs + wave * 512;
  f32x4 acc[4][4] = {};
  for (int k0 = 0; k0 < K; k0 += 32) {
    glds16(Ab + k0, Asl);
    glds16(Ab + 64 * K + k0, Asl + 2048);
    glds16(Bb + k0, Bsl);
    glds16(Bb + 64 * K + k0, Bsl + 2048);
    __syncthreads();  // drains vmcnt -> staged data visible
    bf16x8 af[4], bfr[4];
#pragma unroll
    for (int i = 0; i < 4; i++) {
      af[i] = *(const bf16x8*)(As + (wm * 64 + i * 16 + l15) * 32 + quad * 8);
      bfr[i] = *(const bf16x8*)(Bs + (wn * 64 + i * 16 + l15) * 32 + quad * 8);
    }
#pragma unroll
    for (int i = 0; i < 4; i++)
#pragma unroll
      for (int j = 0; j < 4; j++)
        acc[i][j] = MFMA16(af[i], bfr[j], acc[i][j]);
    __syncthreads();  // protect LDS before next stage
  }
#pragma unroll
  for (int i = 0; i < 4; i++) {
    const int rowb = m0 + wm * 64 + i * 16 + quad * 4;
#pragma unroll
    for (int r = 0; r < 4; r++) {
      const int row = rowb + r;
      if constexpr (MODE == 0) {
        const int bb = row / 343, pos = row % 343;
#pragma unroll
        for (int j = 0; j < 4; j++) {
          const int col = n0 + wn * 64 + j * 16 + l15;
          const int two = col >> 9, hh = (col >> 5) & 15, d = col & 31;
          __bf16* dst = two ? (__bf16*)out1 : (__bf16*)out0;
          dst[((bb * 16 + hh) * 343 + pos) * 32 + d] = (__bf16)acc[i][j][r];
        }
      } else {
        float* o = (float*)out0;
#pragma unroll
        for (int j = 0; j < 4; j++) {
          const int col = n0 + wn * 64 + j * 16 + l15;
          o[row * 512 + col] = acc[i][j][r] + pbias[col];
        }
      }
    }
  }
}

// One workgroup per (b, h): full K/V^T in LDS, per-wave 16-row Q tiles.
// Logits computed directly in log2-domain (q pre-scaled by scale*log2e,
// bias/mask packed pre-scaled); no max-subtraction (|logit2| <~ 20).
__global__ void __launch_bounds__(512, 2)
attn_win(const __bf16* __restrict__ qs, const __bf16* __restrict__ kk,
         const __bf16* __restrict__ vv, const __bf16* __restrict__ bias_pk,
         const __bf16* __restrict__ mask_pk, __bf16* __restrict__ ao) {
  __shared__ __bf16 Ks[352 * 40];    // keys padded to 352 rows, stride 40
  __shared__ __bf16 Vt[32 * 360];    // V transposed [hd][key], stride 360
  __shared__ __bf16 Pb[8 * 640];     // per-wave P staging (C-layout -> A-layout)
  const int bh = blockIdx.x;
  const int b = bh >> 4, h = bh & 15;
  const int tid = threadIdx.x;
  const int lane = tid & 63, wave = tid >> 6;
  const int quad = lane >> 4, l15 = lane & 15;
  const __bf16* ksrc = kk + (b * 16 + h) * 10976;
  const __bf16* vsrc = vv + (b * 16 + h) * 10976;
  for (int i = tid; i < 352 * 4; i += 512) {
    const int row = i >> 2, seg = (i & 3) * 8;
    bf16x8 val;
    if (row < 343) {
      val = *(const bf16x8*)(ksrc + row * 32 + seg);
    } else {
#pragma unroll
      for (int e = 0; e < 8; e++) val[e] = (__bf16)0.f;
    }
    *(bf16x8*)(Ks + row * 40 + seg) = val;
  }
  for (int i = tid; i < 32 * 17; i += 512)
    Vt[(i / 17) * 360 + 343 + (i % 17)] = (__bf16)0.f;
  for (int i = tid; i < 10976; i += 512)
    Vt[(i & 31) * 360 + (i >> 5)] = vsrc[i];
  __syncthreads();

  const int b2 = b >> 6, w = b & 63;
  const __bf16* qbase = qs + (b2 * 16 + h) * 10976;
  const __bf16* bpk = bias_pk + h * 123904;  // 22*11*64*8
  const __bf16* mpk = mask_pk + w * 123904;

  for (int qt = wave; qt < 22; qt += 8) {
    const int rbase = qt * 16 + quad * 4;
    const int arow = qt * 16 + l15;
    const int arowc = arow < 343 ? arow : 342;  // clamp; padded rows discarded
    bf16x8 aq = *(const bf16x8*)(qbase + arowc * 32 + quad * 8);
    const __bf16* bq = bpk + qt * 5632 + lane * 8;  // 11*64*8
    const __bf16* mq = mpk + qt * 5632 + lane * 8;
    f32x4 s[22];
#pragma unroll
    for (int tp = 0; tp < 11; tp++) {
      bf16x8 bb = *(const bf16x8*)(bq + tp * 512);
      bf16x8 mm = *(const bf16x8*)(mq + tp * 512);
#pragma unroll
      for (int t2 = 0; t2 < 2; t2++)
#pragma unroll
        for (int r = 0; r < 4; r++)
          s[2 * tp + t2][r] = (float)bb[t2 * 4 + r] + (float)mm[t2 * 4 + r];
    }
#pragma unroll
    for (int t = 0; t < 22; t++) {
      bf16x8 bk = *(const bf16x8*)(Ks + (t * 16 + l15) * 40 + quad * 8);
      s[t] = MFMA16(aq, bk, s[t]);  // C preloaded with bias+mask (log2 domain)
    }
    float lsum[4] = {0.f, 0.f, 0.f, 0.f};
#pragma unroll
    for (int t = 0; t < 22; t++)
#pragma unroll
      for (int r = 0; r < 4; r++) {
        const float p = __builtin_amdgcn_exp2f(s[t][r]);
        s[t][r] = p;
        lsum[r] += p;
      }
#pragma unroll
    for (int r = 0; r < 4; r++) lsum[r] = qsum4(lsum[r]);
    f32x4 o0 = {0.f, 0.f, 0.f, 0.f}, o1 = {0.f, 0.f, 0.f, 0.f};
    __bf16* pb = Pb + wave * 640;
#pragma unroll
    for (int c = 0; c < 11; c++) {
#pragma unroll
      for (int t2 = 0; t2 < 2; t2++)
#pragma unroll
        for (int r = 0; r < 4; r++)
          pb[(quad * 4 + r) * 40 + t2 * 16 + l15] = (__bf16)s[2 * c + t2][r];
      __threadfence_block();  // wave-private buffer: order writes before read
      bf16x8 ap = *(const bf16x8*)(pb + l15 * 40 + quad * 8);
      bf16x8 bv0 = *(const bf16x8*)(Vt + l15 * 360 + c * 32 + quad * 8);
      bf16x8 bv1 = *(const bf16x8*)(Vt + (16 + l15) * 360 + c * 32 + quad * 8);
      o0 = MFMA16(ap, bv0, o0);
      o1 = MFMA16(ap, bv1, o1);
    }
#pragma unroll
    for (int r = 0; r < 4; r++) {
      const int row = rbase + r;
      if (row < 343) {
        const float inv = __builtin_amdgcn_rcpf(lsum[r]);
        __bf16* op = ao + (b * 343 + row) * 512 + h * 32;
        op[l15] = (__bf16)(o0[r] * inv);
        op[16 + l15] = (__bf16)(o1[r] * inv);
      }
    }
  }
}

extern "C" void kernel_launch(void* const* d_in, const int* in_sizes, int n_in,
                              void* d_out, int out_size, void* d_ws, size_t ws_size,
                              hipStream_t stream) {
  (void)in_sizes; (void)n_in; (void)out_size; (void)ws_size;
  const float* x      = (const float*)d_in[0];
  const float* mask   = (const float*)d_in[4];
  const float* qg     = (const float*)d_in[5];
  const float* kv_w   = (const float*)d_in[6];
  const float* proj_w = (const float*)d_in[7];
  const float* proj_b = (const float*)d_in[8];
  const float* rpb    = (const float*)d_in[9];

  // Workspace layout (16B aligned), total 156,973,056 B. aob aliases xb
  // (xb dead after gemm1; attn writes aob only after gemm1 completes).
  char* ws = (char*)d_ws;
  __bf16* q_bf    = (__bf16*)(ws);               //    702,464  q*scale*log2e [2][16][343][32]
  __bf16* bias_pk = (__bf16*)(ws + 702464);      //  3,964,928  [16][22][11][64][8]
  __bf16* mask_pk = (__bf16*)(ws + 4667392);     // 15,859,712  [64][22][11][64][8]
  __bf16* kvw_b   = (__bf16*)(ws + 20527104);    //  1,048,576
  __bf16* projw_b = (__bf16*)(ws + 21575680);    //    524,288
  __bf16* kb      = (__bf16*)(ws + 22099968);    // 44,957,696  K bf16 [128][16][343][32]
  __bf16* vb      = (__bf16*)(ws + 67057664);    // 44,957,696  V bf16
  __bf16* xb      = (__bf16*)(ws + 112015360);   // 44,957,696  x bf16
  __bf16* aob     = (__bf16*)(ws + 112015360);   // alias: attn out bf16

  const float QSCALE = 0.17677669529663687f * LOG2E;  // hd^-0.5 * log2(e)

  cvt_scale<<<172, 256, 0, stream>>>(qg, q_bf, 43904, QSCALE);   // 351,232 elems = 43904*8
  cvt_scale<<<10976, 256, 0, stream>>>(x, xb, 2809856, 1.f);
  cvt_scale<<<256, 256, 0, stream>>>(kv_w, kvw_b, 65536, 1.f);
  cvt_scale<<<128, 256, 0, stream>>>(proj_w, projw_b, 32768, 1.f);
  pack_bias<<<968, 256, 0, stream>>>(rpb, bias_pk);
  pack_mask<<<3872, 256, 0, stream>>>(mask, mask_pk);
  gemm_async<0><<<dim3(8, 343), 256, 0, stream>>>(xb, kvw_b, 512, kb, vb, nullptr);
  attn_win<<<2048, 512, 0, stream>>>(q_bf, kb, vb, bias_pk, mask_pk, aob);
  gemm_async<1><<<dim3(4, 343), 256, 0, stream>>>(aob, projw_b, 512, d_out, nullptr, proj_b);
}